// Round 1
// baseline (110.621 us; speedup 1.0000x reference)
//
#include <hip/hip_runtime.h>

namespace {

constexpr int kBatch  = 524288;
constexpr int kD      = 16;
constexpr int kOffset = 38167;   // TOTAL - N_GENRES
constexpr int kNG     = 18;

__global__ __launch_bounds__(256) void deepfm_fwd(
    const int*   __restrict__ x_onehot,   // [B,2]  global ids
    const int*   __restrict__ multi_hot,  // [B,18] 0/1
    const float* __restrict__ emb,        // [38185,16]
    const float* __restrict__ fc,         // [38185]
    const float* __restrict__ W1,         // [48,64]
    const float* __restrict__ b1,         // [64]
    const float* __restrict__ W2,         // [64,32]
    const float* __restrict__ b2,         // [32]
    const float* __restrict__ W3,         // [32,16]
    const float* __restrict__ b3,         // [16]
    const float* __restrict__ W4,         // [16,1]
    const float* __restrict__ b4,         // [1]
    const float* __restrict__ bias,       // [1]
    float*       __restrict__ out)        // [B]
{
    const int i = (int)blockIdx.x * 256 + (int)threadIdx.x;
    if (i >= kBatch) return;

    // ---- ids (8B aligned) ----
    const int2 ids = *reinterpret_cast<const int2*>(x_onehot + 2 * (size_t)i);

    // ---- multi-hot mask: 18 ints, row stride 72B (8B aligned) ----
    float m[kNG];
    {
        const int2* mh2 = reinterpret_cast<const int2*>(multi_hot + (size_t)kNG * i);
        #pragma unroll
        for (int g = 0; g < kNG / 2; ++g) {
            const int2 v = mh2[g];
            m[2 * g + 0] = (float)v.x;
            m[2 * g + 1] = (float)v.y;
        }
    }

    // ---- h = [e_user(16) | e_item(16) | e_multihot(16)] ----
    float h[48];
    {
        const float4* eu = reinterpret_cast<const float4*>(emb + (size_t)ids.x * kD);
        #pragma unroll
        for (int q = 0; q < 4; ++q) {
            const float4 a = eu[q];
            h[4*q+0] = a.x; h[4*q+1] = a.y; h[4*q+2] = a.z; h[4*q+3] = a.w;
        }
        const float4* ei = reinterpret_cast<const float4*>(emb + (size_t)ids.y * kD);
        #pragma unroll
        for (int q = 0; q < 4; ++q) {
            const float4 a = ei[q];
            h[16+4*q+0] = a.x; h[16+4*q+1] = a.y; h[16+4*q+2] = a.z; h[16+4*q+3] = a.w;
        }
        #pragma unroll
        for (int d = 0; d < kD; ++d) h[32 + d] = 0.f;
        // genre slice of the table is wave-uniform -> scalar loads (SGPR)
        #pragma unroll
        for (int g = 0; g < kNG; ++g) {
            const float* __restrict__ wg = emb + (size_t)(kOffset + g) * kD;
            #pragma unroll
            for (int d = 0; d < kD; ++d) h[32 + d] = fmaf(m[g], wg[d], h[32 + d]);
        }
    }

    // ---- first-order term + all scalar biases folded in ----
    float lin = bias[0] + b4[0] + fc[ids.x] + fc[ids.y];
    #pragma unroll
    for (int g = 0; g < kNG; ++g) lin = fmaf(m[g], fc[kOffset + g], lin);

    // ---- FM second-order: 0.5*(sum^2 - sum of squares) = sum of pairwise dots ----
    float fm = 0.f;
    #pragma unroll
    for (int d = 0; d < kD; ++d) fm = fmaf(h[d], h[16 + d], fm);
    #pragma unroll
    for (int d = 0; d < kD; ++d) fm = fmaf(h[d], h[32 + d], fm);
    #pragma unroll
    for (int d = 0; d < kD; ++d) fm = fmaf(h[16 + d], h[32 + d], fm);

    // ---- MLP layer 1: 48 -> 64, relu ----
    float h1[64];
    #pragma unroll
    for (int j = 0; j < 64; ++j) h1[j] = b1[j];
    #pragma unroll
    for (int k = 0; k < 48; ++k) {
        const float hk = h[k];
        #pragma unroll
        for (int j = 0; j < 64; ++j) h1[j] = fmaf(hk, W1[k * 64 + j], h1[j]);
    }
    #pragma unroll
    for (int j = 0; j < 64; ++j) h1[j] = fmaxf(h1[j], 0.f);

    // ---- MLP layer 2: 64 -> 32, relu ----
    float h2[32];
    #pragma unroll
    for (int j = 0; j < 32; ++j) h2[j] = b2[j];
    #pragma unroll
    for (int k = 0; k < 64; ++k) {
        const float hk = h1[k];
        #pragma unroll
        for (int j = 0; j < 32; ++j) h2[j] = fmaf(hk, W2[k * 32 + j], h2[j]);
    }
    #pragma unroll
    for (int j = 0; j < 32; ++j) h2[j] = fmaxf(h2[j], 0.f);

    // ---- MLP layer 3: 32 -> 16, relu ----
    float h3[16];
    #pragma unroll
    for (int j = 0; j < 16; ++j) h3[j] = b3[j];
    #pragma unroll
    for (int k = 0; k < 32; ++k) {
        const float hk = h2[k];
        #pragma unroll
        for (int j = 0; j < 16; ++j) h3[j] = fmaf(hk, W3[k * 16 + j], h3[j]);
    }
    #pragma unroll
    for (int j = 0; j < 16; ++j) h3[j] = fmaxf(h3[j], 0.f);

    // ---- MLP layer 4: 16 -> 1 (b4 already folded into lin) ----
    float mlp = 0.f;
    #pragma unroll
    for (int k = 0; k < 16; ++k) mlp = fmaf(h3[k], W4[k], mlp);

    const float x = lin + fm + mlp;
    out[i] = 1.0f / (1.0f + __expf(-x));
}

} // namespace

extern "C" void kernel_launch(void* const* d_in, const int* in_sizes, int n_in,
                              void* d_out, int out_size, void* d_ws, size_t ws_size,
                              hipStream_t stream) {
    (void)in_sizes; (void)n_in; (void)d_ws; (void)ws_size;
    const int*   x_onehot  = (const int*)  d_in[0];
    const int*   multi_hot = (const int*)  d_in[1];
    const float* emb       = (const float*)d_in[2];
    const float* fc        = (const float*)d_in[3];
    const float* W1        = (const float*)d_in[4];
    const float* b1        = (const float*)d_in[5];
    const float* W2        = (const float*)d_in[6];
    const float* b2        = (const float*)d_in[7];
    const float* W3        = (const float*)d_in[8];
    const float* b3        = (const float*)d_in[9];
    const float* W4        = (const float*)d_in[10];
    const float* b4        = (const float*)d_in[11];
    const float* biasp     = (const float*)d_in[12];
    float* out = (float*)d_out;

    const int grid = (kBatch + 255) / 256;   // 2048
    hipLaunchKernelGGL(deepfm_fwd, dim3(grid), dim3(256), 0, stream,
                       x_onehot, multi_hot, emb, fc,
                       W1, b1, W2, b2, W3, b3, W4, b4, biasp, out);
    (void)out_size;
}

// Round 2
// 51.671 us; speedup vs baseline: 2.1409x; 2.1409x over previous
//
#include <hip/hip_runtime.h>

namespace {

constexpr int kBatch  = 524288;
constexpr int kD      = 16;
constexpr int kOffset = 38167;   // TOTAL - N_GENRES
constexpr int kNG     = 18;
constexpr int kStride = 72;      // bf16 elems per LDS row (144B = 9*16B -> bank-window rotation)

typedef __attribute__((ext_vector_type(8))) short short8;   // 8 bf16 = 4 VGPRs (MFMA A/B frag)
typedef __attribute__((ext_vector_type(4))) float f32x4;    // MFMA C/D frag

__device__ __forceinline__ unsigned short f2bf(float f) {   // RNE f32->bf16
    union { float f; unsigned u; } v; v.f = f;
    unsigned r = v.u + 0x7FFFu + ((v.u >> 16) & 1u);
    return (unsigned short)(r >> 16);
}
__device__ __forceinline__ float bf2f(unsigned short s) {
    union { unsigned u; float f; } v; v.u = ((unsigned)s) << 16;
    return v.f;
}
__device__ __forceinline__ unsigned pk2(float a, float b) {
    return (unsigned)f2bf(a) | ((unsigned)f2bf(b) << 16);
}

__global__ __launch_bounds__(256, 3) void deepfm_fwd(
    const int*   __restrict__ x_onehot,   // [B,2]
    const int*   __restrict__ multi_hot,  // [B,18]
    const float* __restrict__ emb,        // [38185,16]
    const float* __restrict__ fc,         // [38185]
    const float* __restrict__ W1,         // [48,64]
    const float* __restrict__ b1,         // [64]
    const float* __restrict__ W2,         // [64,32]
    const float* __restrict__ b2,         // [32]
    const float* __restrict__ W3,         // [32,16]
    const float* __restrict__ b3,         // [16]
    const float* __restrict__ W4,         // [16,1]
    const float* __restrict__ b4,         // [1]
    const float* __restrict__ bias,       // [1]
    float*       __restrict__ out)        // [B]
{
    // Per-wave activation buffers [64 samples][72 bf16], + block-shared W^T tiles.
    __shared__ alignas(16) unsigned short s_act[4][64 * kStride];
    __shared__ alignas(16) unsigned short s_w1t[64 * kStride];   // W1^T [n][k], k 0..47 + zeros 48..63
    __shared__ alignas(16) unsigned short s_w2t[32 * kStride];   // W2^T [n][k], k 0..63
    __shared__ alignas(16) unsigned short s_w3t[16 * kStride];   // W3^T [n][k], k 0..31

    const int t = (int)threadIdx.x;

    // ---- one-time block-cooperative weight staging (f32 -> bf16, transposed) ----
    for (int idx = t; idx < 48 * 64; idx += 256) {               // W1[k*64+n]
        int k = idx >> 6, n = idx & 63;
        s_w1t[n * kStride + k] = f2bf(W1[idx]);
    }
    for (int idx = t; idx < 64 * 16; idx += 256) {               // zero-pad k=48..63
        int n = idx >> 4, k = 48 + (idx & 15);
        s_w1t[n * kStride + k] = 0;
    }
    for (int idx = t; idx < 64 * 32; idx += 256) {               // W2[k*32+n]
        int k = idx >> 5, n = idx & 31;
        s_w2t[n * kStride + k] = f2bf(W2[idx]);
    }
    for (int idx = t; idx < 32 * 16; idx += 256) {               // W3[k*16+n]
        int k = idx >> 4, n = idx & 15;
        s_w3t[n * kStride + k] = f2bf(W3[idx]);
    }
    __syncthreads();

    // ================= per-thread f32 front-end (verified in round 1) =================
    const int i = (int)blockIdx.x * 256 + t;

    const int2 ids = *reinterpret_cast<const int2*>(x_onehot + 2 * (size_t)i);

    float m[kNG];
    {
        const int2* mh2 = reinterpret_cast<const int2*>(multi_hot + (size_t)kNG * i);
        #pragma unroll
        for (int gg = 0; gg < kNG / 2; ++gg) {
            const int2 v = mh2[gg];
            m[2 * gg + 0] = (float)v.x;
            m[2 * gg + 1] = (float)v.y;
        }
    }

    float h[48];
    {
        const float4* eu = reinterpret_cast<const float4*>(emb + (size_t)ids.x * kD);
        #pragma unroll
        for (int q = 0; q < 4; ++q) {
            const float4 a = eu[q];
            h[4*q+0] = a.x; h[4*q+1] = a.y; h[4*q+2] = a.z; h[4*q+3] = a.w;
        }
        const float4* ei = reinterpret_cast<const float4*>(emb + (size_t)ids.y * kD);
        #pragma unroll
        for (int q = 0; q < 4; ++q) {
            const float4 a = ei[q];
            h[16+4*q+0] = a.x; h[16+4*q+1] = a.y; h[16+4*q+2] = a.z; h[16+4*q+3] = a.w;
        }
        #pragma unroll
        for (int d = 0; d < kD; ++d) h[32 + d] = 0.f;
        #pragma unroll
        for (int gg = 0; gg < kNG; ++gg) {                       // wave-uniform table rows
            const float* __restrict__ wg = emb + (size_t)(kOffset + gg) * kD;
            #pragma unroll
            for (int d = 0; d < kD; ++d) h[32 + d] = fmaf(m[gg], wg[d], h[32 + d]);
        }
    }

    float lin = bias[0] + b4[0] + fc[ids.x] + fc[ids.y];
    #pragma unroll
    for (int gg = 0; gg < kNG; ++gg) lin = fmaf(m[gg], fc[kOffset + gg], lin);

    float fm = 0.f;
    #pragma unroll
    for (int d = 0; d < kD; ++d) fm = fmaf(h[d], h[16 + d], fm);
    #pragma unroll
    for (int d = 0; d < kD; ++d) fm = fmaf(h[d], h[32 + d], fm);
    #pragma unroll
    for (int d = 0; d < kD; ++d) fm = fmaf(h[16 + d], h[32 + d], fm);

    // ================= stage h -> per-wave LDS A-matrix (bf16) =================
    const int lane = t & 63;
    const int w    = t >> 6;
    unsigned short* __restrict__ aw = s_act[w];
    {
        unsigned short* ar = aw + lane * kStride;
        #pragma unroll
        for (int q = 0; q < 6; ++q) {
            uint4 d;
            d.x = pk2(h[8*q+0], h[8*q+1]);
            d.y = pk2(h[8*q+2], h[8*q+3]);
            d.z = pk2(h[8*q+4], h[8*q+5]);
            d.w = pk2(h[8*q+6], h[8*q+7]);
            *reinterpret_cast<uint4*>(ar + 8 * q) = d;
        }
        uint4 z; z.x = z.y = z.z = z.w = 0u;                     // K-pad 48..63
        *reinterpret_cast<uint4*>(ar + 48) = z;
        *reinterpret_cast<uint4*>(ar + 56) = z;
    }

    // bias prefetch (per-lane column biases)
    const int c = lane & 15, g = lane >> 4;
    float b1v[4];
    #pragma unroll
    for (int nt = 0; nt < 4; ++nt) b1v[nt] = b1[16 * nt + c];
    float b2v[2]; b2v[0] = b2[c]; b2v[1] = b2[16 + c];
    const float b3v = b3[c];

    const f32x4 z4 = {0.f, 0.f, 0.f, 0.f};

    // ================= L1: h[64x64(pad)] @ W1[64x64(pad)] =================
    f32x4 acc1[4][4];
    #pragma unroll
    for (int mt = 0; mt < 4; ++mt)
        #pragma unroll
        for (int nt = 0; nt < 4; ++nt) acc1[mt][nt] = z4;
    #pragma unroll
    for (int kt = 0; kt < 2; ++kt) {
        short8 af[4], bfr[4];
        #pragma unroll
        for (int mt = 0; mt < 4; ++mt)
            af[mt] = *reinterpret_cast<const short8*>(aw + (16*mt + c) * kStride + 32*kt + 8*g);
        #pragma unroll
        for (int nt = 0; nt < 4; ++nt)
            bfr[nt] = *reinterpret_cast<const short8*>(s_w1t + (16*nt + c) * kStride + 32*kt + 8*g);
        #pragma unroll
        for (int mt = 0; mt < 4; ++mt)
            #pragma unroll
            for (int nt = 0; nt < 4; ++nt)
                acc1[mt][nt] = __builtin_amdgcn_mfma_f32_16x16x32_bf16(af[mt], bfr[nt], acc1[mt][nt], 0, 0, 0);
    }
    // relu+bias -> h1 back into same rows (cols 0..63); D layout: row=(l>>4)*4+r, col=l&15
    #pragma unroll
    for (int mt = 0; mt < 4; ++mt)
        #pragma unroll
        for (int nt = 0; nt < 4; ++nt)
            #pragma unroll
            for (int r = 0; r < 4; ++r) {
                float v = acc1[mt][nt][r] + b1v[nt];
                v = fmaxf(v, 0.f);
                aw[(16*mt + 4*g + r) * kStride + 16*nt + c] = f2bf(v);
            }

    // ================= L2: h1[64x64] @ W2[64x32] =================
    f32x4 acc2[4][2];
    #pragma unroll
    for (int mt = 0; mt < 4; ++mt)
        #pragma unroll
        for (int nt = 0; nt < 2; ++nt) acc2[mt][nt] = z4;
    #pragma unroll
    for (int kt = 0; kt < 2; ++kt) {
        short8 af[4], bfr[2];
        #pragma unroll
        for (int mt = 0; mt < 4; ++mt)
            af[mt] = *reinterpret_cast<const short8*>(aw + (16*mt + c) * kStride + 32*kt + 8*g);
        #pragma unroll
        for (int nt = 0; nt < 2; ++nt)
            bfr[nt] = *reinterpret_cast<const short8*>(s_w2t + (16*nt + c) * kStride + 32*kt + 8*g);
        #pragma unroll
        for (int mt = 0; mt < 4; ++mt)
            #pragma unroll
            for (int nt = 0; nt < 2; ++nt)
                acc2[mt][nt] = __builtin_amdgcn_mfma_f32_16x16x32_bf16(af[mt], bfr[nt], acc2[mt][nt], 0, 0, 0);
    }
    #pragma unroll
    for (int mt = 0; mt < 4; ++mt)
        #pragma unroll
        for (int nt = 0; nt < 2; ++nt)
            #pragma unroll
            for (int r = 0; r < 4; ++r) {
                float v = acc2[mt][nt][r] + b2v[nt];
                v = fmaxf(v, 0.f);
                aw[(16*mt + 4*g + r) * kStride + 16*nt + c] = f2bf(v);
            }

    // ================= L3: h2[64x32] @ W3[32x16] =================
    f32x4 acc3[4];
    #pragma unroll
    for (int mt = 0; mt < 4; ++mt) acc3[mt] = z4;
    {
        short8 af[4];
        #pragma unroll
        for (int mt = 0; mt < 4; ++mt)
            af[mt] = *reinterpret_cast<const short8*>(aw + (16*mt + c) * kStride + 8*g);
        const short8 bfr = *reinterpret_cast<const short8*>(s_w3t + c * kStride + 8*g);
        #pragma unroll
        for (int mt = 0; mt < 4; ++mt)
            acc3[mt] = __builtin_amdgcn_mfma_f32_16x16x32_bf16(af[mt], bfr, acc3[mt], 0, 0, 0);
    }
    #pragma unroll
    for (int mt = 0; mt < 4; ++mt)
        #pragma unroll
        for (int r = 0; r < 4; ++r) {
            float v = acc3[mt][r] + b3v;
            v = fmaxf(v, 0.f);
            aw[(16*mt + 4*g + r) * kStride + c] = f2bf(v);
        }

    // ================= L4 (16 -> 1) per-thread + FM combine =================
    float mlp = 0.f;
    {
        const unsigned short* hr = aw + lane * kStride;
        const uint4 p0 = *reinterpret_cast<const uint4*>(hr);
        const uint4 p1 = *reinterpret_cast<const uint4*>(hr + 8);
        const unsigned pp[8] = {p0.x, p0.y, p0.z, p0.w, p1.x, p1.y, p1.z, p1.w};
        #pragma unroll
        for (int j = 0; j < 8; ++j) {
            mlp = fmaf(bf2f((unsigned short)(pp[j] & 0xFFFFu)), W4[2*j],     mlp);
            mlp = fmaf(bf2f((unsigned short)(pp[j] >> 16)),     W4[2*j + 1], mlp);
        }
    }

    const float x = lin + fm + mlp;
    out[i] = 1.0f / (1.0f + __expf(-x));
}

} // namespace

extern "C" void kernel_launch(void* const* d_in, const int* in_sizes, int n_in,
                              void* d_out, int out_size, void* d_ws, size_t ws_size,
                              hipStream_t stream) {
    (void)in_sizes; (void)n_in; (void)d_ws; (void)ws_size; (void)out_size;
    const int*   x_onehot  = (const int*)  d_in[0];
    const int*   multi_hot = (const int*)  d_in[1];
    const float* emb       = (const float*)d_in[2];
    const float* fc        = (const float*)d_in[3];
    const float* W1        = (const float*)d_in[4];
    const float* b1        = (const float*)d_in[5];
    const float* W2        = (const float*)d_in[6];
    const float* b2        = (const float*)d_in[7];
    const float* W3        = (const float*)d_in[8];
    const float* b3        = (const float*)d_in[9];
    const float* W4        = (const float*)d_in[10];
    const float* b4        = (const float*)d_in[11];
    const float* biasp     = (const float*)d_in[12];
    float* out = (float*)d_out;

    const int grid = kBatch / 256;   // 2048
    hipLaunchKernelGGL(deepfm_fwd, dim3(grid), dim3(256), 0, stream,
                       x_onehot, multi_hot, emb, fc,
                       W1, b1, W2, b2, W3, b3, W4, b4, biasp, out);
}

// Round 4
// 37.362 us; speedup vs baseline: 2.9608x; 1.3830x over previous
//
#include <hip/hip_runtime.h>
#include <hip/hip_bf16.h>

namespace {

constexpr int kBatch  = 524288;
constexpr int kD      = 16;
constexpr int kOffset = 38167;   // TOTAL - N_GENRES
constexpr int kNG     = 18;
constexpr int kAStr   = 72;      // act row stride in bf16 (144B = 9*16B -> 2-way-free b128)

// Weight image layout (bf16 element offsets) — identical in d_ws and LDS.
constexpr int W1A  = 0;     // [64][40]: W1^T k=0..31 in cols 0..31; genre^T stashed in cols 32..39 (row = 4c+g)
constexpr int W1B  = 2560;  // [64][40]: W1^T k=32..47 in cols 0..15; cols 16..39 ZERO (L1 K-pad)
constexpr int W2O  = 5120;  // [32][72]: W2^T k=0..63
constexpr int W3O  = 7424;  // [16][40]: W3^T k=0..31
constexpr int WTOT = 8064;  // elems = 16128 bytes

typedef __attribute__((ext_vector_type(8))) short short8;   // MFMA A/B frag (8 bf16)
typedef __attribute__((ext_vector_type(4))) float f32x4;    // MFMA C/D frag

__device__ __forceinline__ unsigned short f2bf(float f) {
    return __builtin_bit_cast(unsigned short, __float2bfloat16(f));
}
__device__ __forceinline__ unsigned pk2(float a, float b) {
    return (unsigned)f2bf(a) | ((unsigned)f2bf(b) << 16);
}
__device__ __forceinline__ float bf2f(unsigned short s) {
    union { unsigned u; float f; } v; v.u = ((unsigned)s) << 16;
    return v.f;
}

// ---------------- prep: build transposed bf16 weight image in d_ws ----------------
__global__ void prep_weights(const float* __restrict__ emb,
                             const float* __restrict__ W1,
                             const float* __restrict__ W2,
                             const float* __restrict__ W3,
                             unsigned short* __restrict__ wimg)
{
    const int t = (int)threadIdx.x;             // 256 threads, 1 block
    for (int i = t; i < WTOT; i += 256) wimg[i] = 0;
    __syncthreads();
    for (int i = t; i < 64 * 32; i += 256) {    // W1A: k<32
        int n = i >> 5, k = i & 31;
        wimg[W1A + n * 40 + k] = f2bf(W1[k * 64 + n]);
    }
    for (int i = t; i < 512; i += 256) {        // genre^T stash: rows 4c+g, cols 32..39
        int c = i >> 5, r = i & 31, g = r >> 3, j = r & 7;
        int k = 8 * g + j;                      // genre index
        wimg[W1A + (4 * c + g) * 40 + 32 + j] =
            (k < kNG) ? f2bf(emb[(size_t)(kOffset + k) * kD + c]) : (unsigned short)0;
    }
    for (int i = t; i < 64 * 16; i += 256) {    // W1B: k=32..47 -> cols 0..15
        int n = i >> 4, kk = i & 15;
        wimg[W1B + n * 40 + kk] = f2bf(W1[(32 + kk) * 64 + n]);
    }
    for (int i = t; i < 32 * 64; i += 256) {    // W2
        int n = i >> 6, k = i & 63;
        wimg[W2O + n * 72 + k] = f2bf(W2[k * 32 + n]);
    }
    for (int i = t; i < 16 * 32; i += 256) {    // W3
        int n = i >> 5, k = i & 31;
        wimg[W3O + n * 40 + k] = f2bf(W3[k * 16 + n]);
    }
}

// ---------------- main fused kernel ----------------
__global__ __launch_bounds__(256, 3) void deepfm_fwd(
    const int*   __restrict__ x_onehot,
    const int*   __restrict__ multi_hot,
    const float* __restrict__ emb,
    const float* __restrict__ fc,
    const unsigned short* __restrict__ wimg,
    const float* __restrict__ b1,
    const float* __restrict__ b2,
    const float* __restrict__ b3,
    const float* __restrict__ W4,
    const float* __restrict__ b4,
    const float* __restrict__ bias,
    float*       __restrict__ out)
{
    __shared__ alignas(16) unsigned short s_w[WTOT];            // 16128 B
    __shared__ alignas(16) unsigned short s_act[4][64 * kAStr]; // 36864 B  (total 52992 <= 53248)

    const int t = (int)threadIdx.x;

    // ---- stage weight image global->LDS: 1008 uint4 plain copies ----
    {
        const uint4* src = reinterpret_cast<const uint4*>(wimg);
        uint4*       dst = reinterpret_cast<uint4*>(s_w);
        #pragma unroll
        for (int q = 0; q < 4; ++q) {
            const int idx = t + 256 * q;
            if (idx < WTOT / 8) dst[idx] = src[idx];
        }
    }

    const int i    = (int)blockIdx.x * 256 + t;
    const int lane = t & 63;
    const int w    = t >> 6;
    const int c    = lane & 15, g = lane >> 4;
    unsigned short* __restrict__ aw = s_act[w];
    unsigned short* __restrict__ ar = aw + lane * kAStr;

    // ---- independent global loads issued early ----
    int2 mh[9];
    {
        const int2* mh2 = reinterpret_cast<const int2*>(multi_hot + (size_t)kNG * i);
        #pragma unroll
        for (int q = 0; q < 9; ++q) mh[q] = mh2[q];
    }
    const int2 ids = *reinterpret_cast<const int2*>(x_onehot + 2 * (size_t)i);

    float h[32];
    {
        const float4* eu = reinterpret_cast<const float4*>(emb + (size_t)ids.x * kD);
        #pragma unroll
        for (int q = 0; q < 4; ++q) {
            const float4 a = eu[q];
            h[4*q+0] = a.x; h[4*q+1] = a.y; h[4*q+2] = a.z; h[4*q+3] = a.w;
        }
        const float4* ei = reinterpret_cast<const float4*>(emb + (size_t)ids.y * kD);
        #pragma unroll
        for (int q = 0; q < 4; ++q) {
            const float4 a = ei[q];
            h[16+4*q+0] = a.x; h[16+4*q+1] = a.y; h[16+4*q+2] = a.z; h[16+4*q+3] = a.w;
        }
    }

    // per-lane column biases (small L2-resident tables)
    float b1v[4];
    #pragma unroll
    for (int nt = 0; nt < 4; ++nt) b1v[nt] = b1[16 * nt + c];
    float b2v[2]; b2v[0] = b2[c]; b2v[1] = b2[16 + c];
    const float b3v = b3[c];

    // ---- first-order term (mask-select instead of float FMA) ----
    float lin = bias[0] + b4[0] + fc[ids.x] + fc[ids.y];
    #pragma unroll
    for (int q = 0; q < 9; ++q) {
        lin += mh[q].x ? fc[kOffset + 2 * q]     : 0.f;
        lin += mh[q].y ? fc[kOffset + 2 * q + 1] : 0.f;
    }

    // ---- stage m-row (bf16 0/1) into act cols 0..31; zeros for L1 K-pad cols 48..63 ----
    {
        unsigned mw[9];
        #pragma unroll
        for (int q = 0; q < 9; ++q)
            mw[q] = (mh[q].x ? 0x3F80u : 0u) | (mh[q].y ? 0x3F800000u : 0u);
        uint4 v0; v0.x = mw[0]; v0.y = mw[1]; v0.z = mw[2]; v0.w = mw[3];
        uint4 v1; v1.x = mw[4]; v1.y = mw[5]; v1.z = mw[6]; v1.w = mw[7];
        uint4 v2; v2.x = mw[8]; v2.y = 0u;    v2.z = 0u;    v2.w = 0u;
        uint4 vz; vz.x = vz.y = vz.z = vz.w = 0u;
        *reinterpret_cast<uint4*>(ar +  0) = v0;
        *reinterpret_cast<uint4*>(ar +  8) = v1;
        *reinterpret_cast<uint4*>(ar + 16) = v2;
        *reinterpret_cast<uint4*>(ar + 24) = vz;
        *reinterpret_cast<uint4*>(ar + 48) = vz;
        *reinterpret_cast<uint4*>(ar + 56) = vz;
    }

    __syncthreads();   // weight image ready (act buffers are per-wave, no barrier needed)

    const f32x4 z4 = {0.f, 0.f, 0.f, 0.f};

    // ---- embedding-bag via MFMA: e_mh = m @ G  -> act cols 32..47 ----
    {
        const short8 bfrag = *reinterpret_cast<const short8*>(s_w + W1A + (4 * c + g) * 40 + 32);
        short8 af[4];
        #pragma unroll
        for (int mt = 0; mt < 4; ++mt)
            af[mt] = *reinterpret_cast<const short8*>(aw + (16 * mt + c) * kAStr + 8 * g);
        f32x4 accb[4];
        #pragma unroll
        for (int mt = 0; mt < 4; ++mt)
            accb[mt] = __builtin_amdgcn_mfma_f32_16x16x32_bf16(af[mt], bfrag, z4, 0, 0, 0);
        #pragma unroll
        for (int mt = 0; mt < 4; ++mt)
            #pragma unroll
            for (int r = 0; r < 4; ++r)
                aw[(16 * mt + 4 * g + r) * kAStr + 32 + c] = f2bf(accb[mt][r]);
    }

    // ---- pack e_user|e_item -> act cols 0..31 (after bag A-frag reads; DS is in program order) ----
    {
        #pragma unroll
        for (int q = 0; q < 4; ++q) {
            uint4 d;
            d.x = pk2(h[8*q+0], h[8*q+1]);
            d.y = pk2(h[8*q+2], h[8*q+3]);
            d.z = pk2(h[8*q+4], h[8*q+5]);
            d.w = pk2(h[8*q+6], h[8*q+7]);
            *reinterpret_cast<uint4*>(ar + 8 * q) = d;
        }
    }

    // ---- read back e_mh for FM ----
    float fm = 0.f;
    {
        const uint4 p0 = *reinterpret_cast<const uint4*>(ar + 32);
        const uint4 p1 = *reinterpret_cast<const uint4*>(ar + 40);
        const unsigned pp[8] = {p0.x, p0.y, p0.z, p0.w, p1.x, p1.y, p1.z, p1.w};
        float em[16];
        #pragma unroll
        for (int j = 0; j < 8; ++j) {
            em[2*j+0] = bf2f((unsigned short)(pp[j] & 0xFFFFu));
            em[2*j+1] = bf2f((unsigned short)(pp[j] >> 16));
        }
        #pragma unroll
        for (int d = 0; d < kD; ++d) fm = fmaf(h[d], h[16 + d], fm);
        #pragma unroll
        for (int d = 0; d < kD; ++d) fm = fmaf(h[d] + h[16 + d], em[d], fm);
    }

    // ================= L1: act[64x64] @ W1 (K=48 padded to 64) =================
    f32x4 acc1[4][4];
    #pragma unroll
    for (int mt = 0; mt < 4; ++mt)
        #pragma unroll
        for (int nt = 0; nt < 4; ++nt) acc1[mt][nt] = z4;
    #pragma unroll
    for (int kt = 0; kt < 2; ++kt) {
        short8 af[4], bfr[4];
        #pragma unroll
        for (int mt = 0; mt < 4; ++mt)
            af[mt] = *reinterpret_cast<const short8*>(aw + (16*mt + c) * kAStr + 32*kt + 8*g);
        const int wb = kt ? W1B : W1A;
        #pragma unroll
        for (int nt = 0; nt < 4; ++nt)
            bfr[nt] = *reinterpret_cast<const short8*>(s_w + wb + (16*nt + c) * 40 + 8*g);
        #pragma unroll
        for (int mt = 0; mt < 4; ++mt)
            #pragma unroll
            for (int nt = 0; nt < 4; ++nt)
                acc1[mt][nt] = __builtin_amdgcn_mfma_f32_16x16x32_bf16(af[mt], bfr[nt], acc1[mt][nt], 0, 0, 0);
    }
    #pragma unroll
    for (int mt = 0; mt < 4; ++mt)
        #pragma unroll
        for (int nt = 0; nt < 4; ++nt)
            #pragma unroll
            for (int r = 0; r < 4; ++r) {
                const float v = fmaxf(acc1[mt][nt][r] + b1v[nt], 0.f);
                aw[(16*mt + 4*g + r) * kAStr + 16*nt + c] = f2bf(v);
            }

    // ================= L2: h1[64x64] @ W2[64x32] =================
    f32x4 acc2[4][2];
    #pragma unroll
    for (int mt = 0; mt < 4; ++mt)
        #pragma unroll
        for (int nt = 0; nt < 2; ++nt) acc2[mt][nt] = z4;
    #pragma unroll
    for (int kt = 0; kt < 2; ++kt) {
        short8 af[4], bfr[2];
        #pragma unroll
        for (int mt = 0; mt < 4; ++mt)
            af[mt] = *reinterpret_cast<const short8*>(aw + (16*mt + c) * kAStr + 32*kt + 8*g);
        #pragma unroll
        for (int nt = 0; nt < 2; ++nt)
            bfr[nt] = *reinterpret_cast<const short8*>(s_w + W2O + (16*nt + c) * 72 + 32*kt + 8*g);
        #pragma unroll
        for (int mt = 0; mt < 4; ++mt)
            #pragma unroll
            for (int nt = 0; nt < 2; ++nt)
                acc2[mt][nt] = __builtin_amdgcn_mfma_f32_16x16x32_bf16(af[mt], bfr[nt], acc2[mt][nt], 0, 0, 0);
    }
    #pragma unroll
    for (int mt = 0; mt < 4; ++mt)
        #pragma unroll
        for (int nt = 0; nt < 2; ++nt)
            #pragma unroll
            for (int r = 0; r < 4; ++r) {
                const float v = fmaxf(acc2[mt][nt][r] + b2v[nt], 0.f);
                aw[(16*mt + 4*g + r) * kAStr + 16*nt + c] = f2bf(v);
            }

    // ================= L3: h2[64x32] @ W3[32x16] =================
    f32x4 acc3[4];
    #pragma unroll
    for (int mt = 0; mt < 4; ++mt) acc3[mt] = z4;
    {
        const short8 bfr = *reinterpret_cast<const short8*>(s_w + W3O + c * 40 + 8*g);
        short8 af[4];
        #pragma unroll
        for (int mt = 0; mt < 4; ++mt)
            af[mt] = *reinterpret_cast<const short8*>(aw + (16*mt + c) * kAStr + 8*g);
        #pragma unroll
        for (int mt = 0; mt < 4; ++mt)
            acc3[mt] = __builtin_amdgcn_mfma_f32_16x16x32_bf16(af[mt], bfr, acc3[mt], 0, 0, 0);
    }
    #pragma unroll
    for (int mt = 0; mt < 4; ++mt)
        #pragma unroll
        for (int r = 0; r < 4; ++r) {
            const float v = fmaxf(acc3[mt][r] + b3v, 0.f);
            aw[(16*mt + 4*g + r) * kAStr + c] = f2bf(v);
        }

    // ================= L4 (16 -> 1) + combine + sigmoid =================
    float mlp = 0.f;
    {
        const uint4 p0 = *reinterpret_cast<const uint4*>(ar);
        const uint4 p1 = *reinterpret_cast<const uint4*>(ar + 8);
        const unsigned pp[8] = {p0.x, p0.y, p0.z, p0.w, p1.x, p1.y, p1.z, p1.w};
        #pragma unroll
        for (int j = 0; j < 8; ++j) {
            mlp = fmaf(bf2f((unsigned short)(pp[j] & 0xFFFFu)), W4[2*j],     mlp);
            mlp = fmaf(bf2f((unsigned short)(pp[j] >> 16)),     W4[2*j + 1], mlp);
        }
    }

    const float x = lin + fm + mlp;
    out[i] = 1.0f / (1.0f + __expf(-x));
}

} // namespace

extern "C" void kernel_launch(void* const* d_in, const int* in_sizes, int n_in,
                              void* d_out, int out_size, void* d_ws, size_t ws_size,
                              hipStream_t stream) {
    (void)in_sizes; (void)n_in; (void)ws_size; (void)out_size;
    const int*   x_onehot  = (const int*)  d_in[0];
    const int*   multi_hot = (const int*)  d_in[1];
    const float* emb       = (const float*)d_in[2];
    const float* fc        = (const float*)d_in[3];
    const float* W1        = (const float*)d_in[4];
    const float* b1        = (const float*)d_in[5];
    const float* W2        = (const float*)d_in[6];
    const float* b2        = (const float*)d_in[7];
    const float* W3        = (const float*)d_in[8];
    const float* b3        = (const float*)d_in[9];
    const float* W4        = (const float*)d_in[10];
    const float* b4        = (const float*)d_in[11];
    const float* biasp     = (const float*)d_in[12];
    float* out = (float*)d_out;
    unsigned short* wimg = (unsigned short*)d_ws;

    hipLaunchKernelGGL(prep_weights, dim3(1), dim3(256), 0, stream,
                       emb, W1, W2, W3, wimg);
    hipLaunchKernelGGL(deepfm_fwd, dim3(kBatch / 256), dim3(256), 0, stream,
                       x_onehot, multi_hot, emb, fc, wimg,
                       b1, b2, b3, W4, b4, biasp, out);
}